// Round 6
// baseline (148.054 us; speedup 1.0000x reference)
//
#include <hip/hip_runtime.h>

#define CIN   512
#define COUT  256
#define HWDIM 32
#define NBATCH 64
#define PIX_PER_IMG (HWDIM * HWDIM)          // 1024
#define NPIX (NBATCH * PIX_PER_IMG)          // 65536

typedef __attribute__((ext_vector_type(4))) int i32x4;

// ---------------- workspace layout ----------------
#define OFF_XB    ((size_t)0)
#define OFF_WB    ((size_t)33554432)
#define OFF_CONV  ((size_t)34734080)
#define OFF_STATS ((size_t)68288512)         // sum_sh[8][256] int (8192) + sumsq_sh[8][256] u64 (16384)
#define OFF_SCALE (OFF_STATS + 24576)
#define OFF_SHIFT (OFF_SCALE + 1024)
#define OFF_ZERO  (OFF_SHIFT + 1024)

// ---------------- pack x: f32 NCHW -> int8 sign NHWC ----------------
__global__ __launch_bounds__(256) void pack_x_kernel(const float* __restrict__ x,
                                                     signed char* __restrict__ xb) {
  const int plane = blockIdx.x;            // n*32 + h, 2048 planes
  const int n = plane >> 5, h = plane & 31;
  __shared__ int tile[HWDIM * 130];        // [w][130] ints (4 ci-bytes each)
  const int t = threadIdx.x;
  const float* xp = x + (size_t)n * CIN * PIX_PER_IMG + (size_t)h * HWDIM;
#define SB(v) ((v) >= 0.f ? 0x01u : 0xFFu)
#pragma unroll
  for (int it = 0; it < 4; ++it) {
    int idx = it * 256 + t;                // 0..1023
    int cib = idx >> 3;                    // ci block 0..127 (ci = cib*4)
    int w4 = (idx & 7) << 2;               // 0,4,...,28
    const float* p0 = xp + (size_t)(cib * 4 + 0) * PIX_PER_IMG + w4;
    float4 fa = *reinterpret_cast<const float4*>(p0);
    float4 fb = *reinterpret_cast<const float4*>(p0 + PIX_PER_IMG);
    float4 fc = *reinterpret_cast<const float4*>(p0 + 2 * PIX_PER_IMG);
    float4 fd = *reinterpret_cast<const float4*>(p0 + 3 * PIX_PER_IMG);
    unsigned o0 = SB(fa.x) | (SB(fb.x) << 8) | (SB(fc.x) << 16) | (SB(fd.x) << 24);
    unsigned o1 = SB(fa.y) | (SB(fb.y) << 8) | (SB(fc.y) << 16) | (SB(fd.y) << 24);
    unsigned o2 = SB(fa.z) | (SB(fb.z) << 8) | (SB(fc.z) << 16) | (SB(fd.z) << 24);
    unsigned o3 = SB(fa.w) | (SB(fb.w) << 8) | (SB(fc.w) << 16) | (SB(fd.w) << 24);
    tile[(w4 + 0) * 130 + cib] = (int)o0;
    tile[(w4 + 1) * 130 + cib] = (int)o1;
    tile[(w4 + 2) * 130 + cib] = (int)o2;
    tile[(w4 + 3) * 130 + cib] = (int)o3;
  }
  __syncthreads();
  int2* xo = reinterpret_cast<int2*>(xb + (size_t)plane * (HWDIM * CIN));
#pragma unroll
  for (int it = 0; it < 8; ++it) {
    int cc = it * 256 + t;                 // 8B chunk id 0..2047
    int w = cc >> 6, c8 = cc & 63;
    int2 v = make_int2(tile[w * 130 + c8 * 2], tile[w * 130 + c8 * 2 + 1]);
    xo[cc] = v;
  }
}

// ---------------- pack W: f32 OIHW -> int8 sign [tap][co][ci] ----------------
__global__ __launch_bounds__(256) void pack_w_kernel(const float* __restrict__ W,
                                                     signed char* __restrict__ wb) {
  int idx = blockIdx.x * 256 + threadIdx.x;     // 9*256*512 total
  int tap = idx / (COUT * CIN);
  int rem = idx - tap * (COUT * CIN);
  int co = rem >> 9;
  int ci = rem & 511;
  float v = W[((size_t)co * CIN + ci) * 9 + tap];
  wb[idx] = v >= 0.f ? 1 : -1;
}

// ---------------- conv: i8 MFMA GEMM, M=256 tile, 4-ring, 2-phase-per-step ----
#define BM 256
#define BK 64
#define NSTEP 72
#define ABYTES (BM * BK)             // 16384
#define BUFB   (ABYTES + COUT * BK)  // 32768
#define LDS_TOTAL (4 * BUFB)         // 131072

__device__ __forceinline__ void load16(const void* g, void* l) {
  __builtin_amdgcn_global_load_lds((const __attribute__((address_space(1))) void*)g,
                                   (__attribute__((address_space(3))) void*)l, 16, 0, 0);
}

__global__ __launch_bounds__(512, 2) void conv_kernel(
    const signed char* __restrict__ xb,    // [2048][32][512]
    const signed char* __restrict__ wb,    // [9][256][512]
    short* __restrict__ cv,                // [64][256][1024]
    const signed char* __restrict__ zp,
    int* __restrict__ sum,                 // [8][256] shadows
    unsigned long long* __restrict__ sumsq) {
  extern __shared__ signed char lds[];       // 128 KB, ring of 4
  const int t = threadIdx.x;
  const int wid = t >> 6, lane = t & 63;
  const int b = blockIdx.x;                  // 0..255, one per CU
  const int nimg = b >> 2;
  const int h0 = (b & 3) * 8;                // 8 image rows per block

  const int wr = wid >> 2;                   // 0..1   (M dir, 128 rows each)
  const int wc = wid & 3;                    // 0..3   (N dir, 64 cols each)

  i32x4 acc[8][4];
#pragma unroll
  for (int m = 0; m < 8; ++m)
#pragma unroll
    for (int n = 0; n < 4; ++n) { i32x4 z = {0, 0, 0, 0}; acc[m][n] = z; }

  // A staging half: 2x16B loads/thread, linear LDS dest, T2-swizzled source slot
  auto stageA = [&](int buf, int step) {
    const int tap = step >> 3;
    const int s   = step & 7;
    const int ci0 = s << 6;
    const int dh = tap / 3 - 1, dw = tap % 3 - 1;
    signed char* dst = lds + buf * BUFB;
#pragma unroll
    for (int it = 0; it < 2; ++it) {
      int c = it * 512 + t;                  // A chunk 0..1023
      int r = c >> 2;                        // pixel row 0..255
      int soff = ((c & 3) ^ ((c >> 3) & 3)) << 4;
      int hs = h0 + (r >> 5) + dh;
      int ws = (r & 31) + dw;
      bool ok = ((unsigned)hs < 32u) && ((unsigned)ws < 32u);
      const signed char* src = ok
          ? xb + (((size_t)(nimg * 32 + hs) * 32 + ws) * CIN + ci0 + soff)
          : zp + soff;
      load16(src, (void*)(dst + c * 16));
    }
  };
  // B staging half: 2x16B loads/thread
  auto stageB = [&](int buf, int step) {
    const int tap = step >> 3;
    const int s   = step & 7;
    const int ci0 = s << 6;
    signed char* dst = lds + buf * BUFB;
#pragma unroll
    for (int it = 0; it < 2; ++it) {
      int c = it * 512 + t;                  // B chunk 0..1023
      int co = c >> 2;
      int soff = ((c & 3) ^ ((c >> 3) & 3)) << 4;
      const signed char* src = wb + ((size_t)tap * COUT + co) * CIN + ci0 + soff;
      load16(src, (void*)(dst + ABYTES + c * 16));
    }
  };

  // read-side offsets (swizzle XOR uniform across m/n)
  const int koff = (lane >> 4) << 4;
  const int ksw  = (((lane >> 1) & 3) << 4);
  int aoff[8], boff[4];
#pragma unroll
  for (int m = 0; m < 8; ++m) {
    int row = wr * 128 + m * 16 + (lane & 15);
    aoff[m] = row * BK + (koff ^ ksw);
  }
#pragma unroll
  for (int n = 0; n < 4; ++n) {
    int col = wc * 64 + n * 16 + (lane & 15);
    boff[n] = ABYTES + col * BK + (koff ^ ksw);
  }

  // prologue: prefetch depth 3 (12 loads), wait for buf0's 4
  stageA(0, 0); stageB(0, 0);
  stageA(1, 1); stageB(1, 1);
  stageA(2, 2); stageB(2, 2);
  asm volatile("s_waitcnt vmcnt(8)" ::: "memory");
  __builtin_amdgcn_s_barrier();

  for (int s = 0; s < NSTEP; ++s) {
    const signed char* base = lds + (s & 3) * BUFB;
    i32x4 af[8], bf[4];
    // ---- phase 1: frags m0..3 + B, stage-A of s+3, MFMA quadrant 1 ----
#pragma unroll
    for (int m = 0; m < 4; ++m)
      af[m] = *reinterpret_cast<const i32x4*>(base + aoff[m]);
#pragma unroll
    for (int n = 0; n < 4; ++n)
      bf[n] = *reinterpret_cast<const i32x4*>(base + boff[n]);
    if (s + 3 < NSTEP) stageA((s + 3) & 3, s + 3);
    __builtin_amdgcn_s_barrier();
    asm volatile("s_waitcnt lgkmcnt(0)" ::: "memory");
    __builtin_amdgcn_sched_barrier(0);
    __builtin_amdgcn_s_setprio(1);
#pragma unroll
    for (int m = 0; m < 4; ++m)
#pragma unroll
      for (int n = 0; n < 4; ++n)
        acc[m][n] = __builtin_amdgcn_mfma_i32_16x16x64_i8(af[m], bf[n], acc[m][n], 0, 0, 0);
    __builtin_amdgcn_s_setprio(0);
    __builtin_amdgcn_s_barrier();
    // ---- phase 2: frags m4..7, stage-B of s+3, counted vmcnt, MFMA quadrant 2 ----
#pragma unroll
    for (int m = 4; m < 8; ++m)
      af[m] = *reinterpret_cast<const i32x4*>(base + aoff[m]);
    if (s + 3 < NSTEP) stageB((s + 3) & 3, s + 3);
    if (s <= NSTEP - 4)      asm volatile("s_waitcnt vmcnt(8)" ::: "memory");
    else if (s == NSTEP - 3) asm volatile("s_waitcnt vmcnt(4)" ::: "memory");
    else                     asm volatile("s_waitcnt vmcnt(0)" ::: "memory");
    __builtin_amdgcn_s_barrier();
    asm volatile("s_waitcnt lgkmcnt(0)" ::: "memory");
    __builtin_amdgcn_sched_barrier(0);
    __builtin_amdgcn_s_setprio(1);
#pragma unroll
    for (int m = 4; m < 8; ++m)
#pragma unroll
      for (int n = 0; n < 4; ++n)
        acc[m][n] = __builtin_amdgcn_mfma_i32_16x16x64_i8(af[m], bf[n], acc[m][n], 0, 0, 0);
    __builtin_amdgcn_s_setprio(0);
    __builtin_amdgcn_s_barrier();
  }

  // epilogue A: write int16 conv output, NCHW
  const int P0 = b * BM;
#pragma unroll
  for (int m = 0; m < 8; ++m) {
#pragma unroll
    for (int n = 0; n < 4; ++n) {
      int row = wr * 128 + m * 16 + ((lane >> 4) << 2);
      int co = wc * 64 + n * 16 + (lane & 15);
      int P = P0 + row;
      int ni = P >> 10;
      int hw = P & 1023;
      short4 v = make_short4((short)acc[m][n][0], (short)acc[m][n][1],
                             (short)acc[m][n][2], (short)acc[m][n][3]);
      *reinterpret_cast<short4*>(cv + (((size_t)ni * COUT + co) << 10) + hw) = v;
    }
  }

  // epilogue B: fused per-channel sum / sumsq into 8 shadow copies (exact integers)
  int* sumS = sum + (b & 7) * COUT;
  unsigned long long* sqS = sumsq + (b & 7) * COUT;
#pragma unroll
  for (int n = 0; n < 4; ++n) {
    int s1 = 0;
    long long s2 = 0;
#pragma unroll
    for (int m = 0; m < 8; ++m)
#pragma unroll
      for (int j = 0; j < 4; ++j) {
        int v = acc[m][n][j];
        s1 += v;
        s2 += (long long)v * v;
      }
    s1 += __shfl_xor(s1, 16, 64);
    s1 += __shfl_xor(s1, 32, 64);
    s2 += __shfl_xor(s2, 16, 64);
    s2 += __shfl_xor(s2, 32, 64);
    if (lane < 16) {
      int c = wc * 64 + n * 16 + lane;
      atomicAdd(&sumS[c], s1);
      atomicAdd(&sqS[c], (unsigned long long)s2);
    }
  }
}

// ---------------- stats -> scale/shift (sums 8 shadows) ----------------
__global__ void stats_kernel(const int* __restrict__ sum,
                             const unsigned long long* __restrict__ sumsq,
                             const float* __restrict__ gamma,
                             const float* __restrict__ beta,
                             float* __restrict__ scale,
                             float* __restrict__ shift) {
  int co = threadIdx.x;
  long long s1 = 0, s2 = 0;
#pragma unroll
  for (int k = 0; k < 8; ++k) {
    s1 += sum[k * COUT + co];
    s2 += (long long)sumsq[k * COUT + co];
  }
  double cnt = (double)NPIX;
  double mean = (double)s1 / cnt;
  double ex2 = (double)s2 / cnt;
  double var = ex2 - mean * mean;
  double rs = 1.0 / sqrt(var + 1e-5);
  float g = gamma[co];
  scale[co] = (float)rs * g;
  shift[co] = beta[co] - (float)(mean * rs) * g;
}

// ---------------- normalize + residual + clip (8 elems/thread) ----------------
__global__ __launch_bounds__(256) void final_kernel(const short* __restrict__ cv,
                                                    const float* __restrict__ x,
                                                    const float* __restrict__ scale,
                                                    const float* __restrict__ shift,
                                                    float* __restrict__ out) {
  size_t i = ((size_t)blockIdx.x * 256 + threadIdx.x) * 8;
  int co = (int)((i >> 10) & 255);
  size_t n = i >> 18;
  size_t hw = i & 1023;
  short4 c0 = *reinterpret_cast<const short4*>(cv + i);
  short4 c1 = *reinterpret_cast<const short4*>(cv + i + 4);
  const float* xr = x + ((n * CIN + co) << 10) + hw;
  float4 r0 = *reinterpret_cast<const float4*>(xr);
  float4 r1 = *reinterpret_cast<const float4*>(xr + 4);
  float sc = scale[co], sh = shift[co];
  float4 o0, o1;
  o0.x = fminf(1.f, fmaxf(-1.f, (float)c0.x * sc + sh + r0.x));
  o0.y = fminf(1.f, fmaxf(-1.f, (float)c0.y * sc + sh + r0.y));
  o0.z = fminf(1.f, fmaxf(-1.f, (float)c0.z * sc + sh + r0.z));
  o0.w = fminf(1.f, fmaxf(-1.f, (float)c0.w * sc + sh + r0.w));
  o1.x = fminf(1.f, fmaxf(-1.f, (float)c1.x * sc + sh + r1.x));
  o1.y = fminf(1.f, fmaxf(-1.f, (float)c1.y * sc + sh + r1.y));
  o1.z = fminf(1.f, fmaxf(-1.f, (float)c1.z * sc + sh + r1.z));
  o1.w = fminf(1.f, fmaxf(-1.f, (float)c1.w * sc + sh + r1.w));
  *reinterpret_cast<float4*>(out + i) = o0;
  *reinterpret_cast<float4*>(out + i + 4) = o1;
}

extern "C" void kernel_launch(void* const* d_in, const int* in_sizes, int n_in,
                              void* d_out, int out_size, void* d_ws, size_t ws_size,
                              hipStream_t stream) {
  const float* x     = (const float*)d_in[0];
  const float* W     = (const float*)d_in[1];
  const float* gamma = (const float*)d_in[2];
  const float* beta  = (const float*)d_in[3];
  float* out = (float*)d_out;
  char* ws = (char*)d_ws;

  signed char* xb = (signed char*)(ws + OFF_XB);
  signed char* wb = (signed char*)(ws + OFF_WB);
  short* cv = (short*)(ws + OFF_CONV);
  int* sum = (int*)(ws + OFF_STATS);
  unsigned long long* sumsq = (unsigned long long*)(ws + OFF_STATS + 8192);
  float* scale = (float*)(ws + OFF_SCALE);
  float* shift = (float*)(ws + OFF_SHIFT);
  signed char* zp = (signed char*)(ws + OFF_ZERO);

  // allow 128 KB dynamic LDS (host-side metadata; capture-safe, idempotent)
  hipFuncSetAttribute((const void*)conv_kernel,
                      hipFuncAttributeMaxDynamicSharedMemorySize, LDS_TOTAL);

  // zero shadows + scale/shift + zero page (26,880 B)
  hipMemsetAsync(ws + OFF_STATS, 0, 26880, stream);

  pack_x_kernel<<<NBATCH * HWDIM, 256, 0, stream>>>(x, xb);
  pack_w_kernel<<<(9 * COUT * CIN) / 256, 256, 0, stream>>>(W, wb);
  conv_kernel<<<NPIX / BM, 512, LDS_TOTAL, stream>>>(xb, wb, cv, zp, sum, sumsq);
  stats_kernel<<<1, 256, 0, stream>>>(sum, sumsq, gamma, beta, scale, shift);
  final_kernel<<<(NBATCH * COUT * PIX_PER_IMG) / (256 * 8), 256, 0, stream>>>(
      cv, x, scale, shift, out);
}

// Round 7
// 135.137 us; speedup vs baseline: 1.0956x; 1.0956x over previous
//
#include <hip/hip_runtime.h>

#define CIN   512
#define COUT  256
#define HWDIM 32
#define NBATCH 64
#define PIX_PER_IMG (HWDIM * HWDIM)          // 1024
#define NPIX (NBATCH * PIX_PER_IMG)          // 65536

typedef __attribute__((ext_vector_type(4))) int i32x4;

// ---------------- workspace layout ----------------
#define OFF_XB    ((size_t)0)
#define OFF_WB    ((size_t)33554432)
#define OFF_CONV  ((size_t)34734080)
#define OFF_STATS ((size_t)68288512)         // sum[8][256] i32 (8192) + sumsq[8][256] u64 (16384)
#define OFF_SCALE (OFF_STATS + 24576)
#define OFF_SHIFT (OFF_SCALE + 1024)
#define OFF_ZERO  (OFF_SHIFT + 1024)         // 1024 B zero page (covers soff + s*64 reach)

// ---------------- pack x: f32 NCHW -> int8 sign NHWC ----------------
__global__ __launch_bounds__(256) void pack_x_kernel(const float* __restrict__ x,
                                                     signed char* __restrict__ xb) {
  const int plane = blockIdx.x;            // n*32 + h, 2048 planes
  const int n = plane >> 5, h = plane & 31;
  __shared__ int tile[HWDIM * 130];        // [w][130] ints (4 ci-bytes each)
  const int t = threadIdx.x;
  const float* xp = x + (size_t)n * CIN * PIX_PER_IMG + (size_t)h * HWDIM;
#define SB(v) ((v) >= 0.f ? 0x01u : 0xFFu)
#pragma unroll
  for (int it = 0; it < 4; ++it) {
    int idx = it * 256 + t;                // 0..1023
    int cib = idx >> 3;                    // ci block 0..127 (ci = cib*4)
    int w4 = (idx & 7) << 2;               // 0,4,...,28
    const float* p0 = xp + (size_t)(cib * 4 + 0) * PIX_PER_IMG + w4;
    float4 fa = *reinterpret_cast<const float4*>(p0);
    float4 fb = *reinterpret_cast<const float4*>(p0 + PIX_PER_IMG);
    float4 fc = *reinterpret_cast<const float4*>(p0 + 2 * PIX_PER_IMG);
    float4 fd = *reinterpret_cast<const float4*>(p0 + 3 * PIX_PER_IMG);
    unsigned o0 = SB(fa.x) | (SB(fb.x) << 8) | (SB(fc.x) << 16) | (SB(fd.x) << 24);
    unsigned o1 = SB(fa.y) | (SB(fb.y) << 8) | (SB(fc.y) << 16) | (SB(fd.y) << 24);
    unsigned o2 = SB(fa.z) | (SB(fb.z) << 8) | (SB(fc.z) << 16) | (SB(fd.z) << 24);
    unsigned o3 = SB(fa.w) | (SB(fb.w) << 8) | (SB(fc.w) << 16) | (SB(fd.w) << 24);
    tile[(w4 + 0) * 130 + cib] = (int)o0;
    tile[(w4 + 1) * 130 + cib] = (int)o1;
    tile[(w4 + 2) * 130 + cib] = (int)o2;
    tile[(w4 + 3) * 130 + cib] = (int)o3;
  }
  __syncthreads();
  int2* xo = reinterpret_cast<int2*>(xb + (size_t)plane * (HWDIM * CIN));
#pragma unroll
  for (int it = 0; it < 8; ++it) {
    int cc = it * 256 + t;                 // 8B chunk id 0..2047
    int w = cc >> 6, c8 = cc & 63;
    int2 v = make_int2(tile[w * 130 + c8 * 2], tile[w * 130 + c8 * 2 + 1]);
    xo[cc] = v;
  }
}

// ---------------- pack W: f32 OIHW -> int8 sign [tap][co][ci] ----------------
__global__ __launch_bounds__(256) void pack_w_kernel(const float* __restrict__ W,
                                                     signed char* __restrict__ wb) {
  int idx = blockIdx.x * 256 + threadIdx.x;     // 9*256*512 total
  int tap = idx / (COUT * CIN);
  int rem = idx - tap * (COUT * CIN);
  int co = rem >> 9;
  int ci = rem & 511;
  float v = W[((size_t)co * CIN + ci) * 9 + tap];
  wb[idx] = v >= 0.f ? 1 : -1;
}

// ---------------- conv: i8 MFMA GEMM, tap-outer loop, ring-4, compiler-scheduled ----
#define BM 256
#define BK 64
#define ABYTES (BM * BK)             // 16384
#define BUFB   (ABYTES + COUT * BK)  // 32768
#define LDS_TOTAL (4 * BUFB)         // 131072

__device__ __forceinline__ void load16(const void* g, void* l) {
  __builtin_amdgcn_global_load_lds((const __attribute__((address_space(1))) void*)g,
                                   (__attribute__((address_space(3))) void*)l, 16, 0, 0);
}

__global__ __launch_bounds__(512, 2) void conv_kernel(
    const signed char* __restrict__ xb,    // [2048][32][512]
    const signed char* __restrict__ wb,    // [9][256][512]
    short* __restrict__ cv,                // [64][256][1024]
    const signed char* __restrict__ zp,
    int* __restrict__ sum,                 // [8][256] shadows
    unsigned long long* __restrict__ sumsq) {
  extern __shared__ signed char lds[];       // 128 KB, ring of 4
  const int t = threadIdx.x;
  const int wid = t >> 6, lane = t & 63;
  const int b = blockIdx.x;                  // 0..255, one per CU
  const int nimg = b >> 2;
  const int h0 = (b & 3) * 8;                // 8 image rows per block

  const int wr = wid >> 2;                   // 0..1   (M dir, 128 rows each)
  const int wc = wid & 3;                    // 0..3   (N dir, 64 cols each)

  i32x4 acc[8][4];
#pragma unroll
  for (int m = 0; m < 8; ++m)
#pragma unroll
    for (int n = 0; n < 4; ++n) { i32x4 z = {0, 0, 0, 0}; acc[m][n] = z; }

  // staging chunk ids (2 A-chunks + 2 B-chunks per thread)
  const int c0 = t, c1 = 512 + t;

  // per-tap base pointers (halo/zp logic hoisted out of the step loop)
  auto abase = [&](int tap, int c) -> const signed char* {
    int r = c >> 2;                          // pixel row 0..255
    int soff = ((c & 3) ^ ((c >> 3) & 3)) << 4;   // T2-swizzled source slot
    int dh = tap / 3 - 1, dw = tap % 3 - 1;
    int hs = h0 + (r >> 5) + dh;
    int ws2 = (r & 31) + dw;
    bool ok = ((unsigned)hs < 32u) && ((unsigned)ws2 < 32u);
    return ok ? xb + ((size_t)((nimg * 32 + hs) * 32 + ws2) * CIN) + soff
              : zp + soff;
  };
  auto bbase = [&](int tap, int c) -> const signed char* {
    int co = c >> 2;
    int soff = ((c & 3) ^ ((c >> 3) & 3)) << 4;
    return wb + ((size_t)tap * COUT + co) * CIN + soff;
  };

  // read-side frag offsets (swizzle XOR uniform across m/n)
  const int koff = (lane >> 4) << 4;
  const int ksw  = (((lane >> 1) & 3) << 4);
  int aoff[8], boff[4];
#pragma unroll
  for (int m = 0; m < 8; ++m) {
    int row = wr * 128 + m * 16 + (lane & 15);
    aoff[m] = row * BK + (koff ^ ksw);
  }
#pragma unroll
  for (int n = 0; n < 4; ++n) {
    int col = wc * 64 + n * 16 + (lane & 15);
    boff[n] = ABYTES + col * BK + (koff ^ ksw);
  }

  const signed char *a0 = abase(0, c0), *a1 = abase(0, c1);
  const signed char *b0 = bbase(0, c0), *b1 = bbase(0, c1);

  // prologue: stage steps 0..2 (tap 0) into bufs 0..2; depth-3 prefetch
#pragma unroll
  for (int s = 0; s < 3; ++s) {
    signed char* d = lds + s * BUFB;
    load16(a0 + s * 64, (void*)(d + c0 * 16));
    load16(a1 + s * 64, (void*)(d + c1 * 16));
    load16(b0 + s * 64, (void*)(d + ABYTES + c0 * 16));
    load16(b1 + s * 64, (void*)(d + ABYTES + c1 * 16));
  }
  asm volatile("s_waitcnt vmcnt(8)" ::: "memory");   // buf0's 4 loads done
  __builtin_amdgcn_s_barrier();

  for (int tap = 0; tap < 9; ++tap) {
    // next-tap bases (computed once per tap, ~40 VALU amortized over 8 steps)
    const signed char *na0, *na1, *nb0, *nb1;
    if (tap < 8) {
      na0 = abase(tap + 1, c0); na1 = abase(tap + 1, c1);
      nb0 = bbase(tap + 1, c0); nb1 = bbase(tap + 1, c1);
    } else {
      na0 = na1 = nb0 = nb1 = zp;
    }
#pragma unroll
    for (int s = 0; s < 8; ++s) {            // global step = tap*8 + s; (step&3) == (s&3)
      // stage step+3 (static addressing: base + s*64 immediate)
      if (s <= 4) {
        signed char* d = lds + ((s + 3) & 3) * BUFB;
        load16(a0 + (s + 3) * 64, (void*)(d + c0 * 16));
        load16(a1 + (s + 3) * 64, (void*)(d + c1 * 16));
        load16(b0 + (s + 3) * 64, (void*)(d + ABYTES + c0 * 16));
        load16(b1 + (s + 3) * 64, (void*)(d + ABYTES + c1 * 16));
      } else if (tap < 8) {
        signed char* d = lds + ((s + 3) & 3) * BUFB;
        load16(na0 + (s - 5) * 64, (void*)(d + c0 * 16));
        load16(na1 + (s - 5) * 64, (void*)(d + c1 * 16));
        load16(nb0 + (s - 5) * 64, (void*)(d + ABYTES + c0 * 16));
        load16(nb1 + (s - 5) * 64, (void*)(d + ABYTES + c1 * 16));
      }
      // frag reads + MFMA: plain loads, compiler emits fine-grained lgkm waits
      const signed char* base = lds + (s & 3) * BUFB;
      i32x4 af[8], bf[4];
#pragma unroll
      for (int n = 0; n < 4; ++n)
        bf[n] = *reinterpret_cast<const i32x4*>(base + boff[n]);
#pragma unroll
      for (int m = 0; m < 8; ++m)
        af[m] = *reinterpret_cast<const i32x4*>(base + aoff[m]);
      __builtin_amdgcn_s_setprio(1);
#pragma unroll
      for (int m = 0; m < 8; ++m)
#pragma unroll
        for (int n = 0; n < 4; ++n)
          acc[m][n] = __builtin_amdgcn_mfma_i32_16x16x64_i8(af[m], bf[n], acc[m][n], 0, 0, 0);
      __builtin_amdgcn_s_setprio(0);
      // counted vmcnt: next step's 4 staging loads landed; never drain mid-loop
      if (tap < 8 || s < 5) asm volatile("s_waitcnt vmcnt(8)" ::: "memory");
      else if (s == 5)      asm volatile("s_waitcnt vmcnt(4)" ::: "memory");
      else                  asm volatile("s_waitcnt vmcnt(0)" ::: "memory");
      __builtin_amdgcn_s_barrier();          // single barrier per step
    }
    a0 = na0; a1 = na1; b0 = nb0; b1 = nb1;
  }

  // epilogue A: write int16 conv output, NCHW
  const int P0 = b * BM;
#pragma unroll
  for (int m = 0; m < 8; ++m) {
#pragma unroll
    for (int n = 0; n < 4; ++n) {
      int row = wr * 128 + m * 16 + ((lane >> 4) << 2);
      int co = wc * 64 + n * 16 + (lane & 15);
      int P = P0 + row;
      int ni = P >> 10;
      int hw = P & 1023;
      short4 v = make_short4((short)acc[m][n][0], (short)acc[m][n][1],
                             (short)acc[m][n][2], (short)acc[m][n][3]);
      *reinterpret_cast<short4*>(cv + (((size_t)ni * COUT + co) << 10) + hw) = v;
    }
  }

  // epilogue B: fused per-channel sum / sumsq into 8 shadow copies (exact integers)
  int* sumS = sum + (b & 7) * COUT;
  unsigned long long* sqS = sumsq + (b & 7) * COUT;
#pragma unroll
  for (int n = 0; n < 4; ++n) {
    int s1 = 0;
    long long s2 = 0;
#pragma unroll
    for (int m = 0; m < 8; ++m)
#pragma unroll
      for (int j = 0; j < 4; ++j) {
        int v = acc[m][n][j];
        s1 += v;
        s2 += (long long)v * v;
      }
    s1 += __shfl_xor(s1, 16, 64);
    s1 += __shfl_xor(s1, 32, 64);
    s2 += __shfl_xor(s2, 16, 64);
    s2 += __shfl_xor(s2, 32, 64);
    if (lane < 16) {
      int c = wc * 64 + n * 16 + lane;
      atomicAdd(&sumS[c], s1);
      atomicAdd(&sqS[c], (unsigned long long)s2);
    }
  }
}

// ---------------- stats -> scale/shift (sums 8 shadows) ----------------
__global__ void stats_kernel(const int* __restrict__ sum,
                             const unsigned long long* __restrict__ sumsq,
                             const float* __restrict__ gamma,
                             const float* __restrict__ beta,
                             float* __restrict__ scale,
                             float* __restrict__ shift) {
  int co = threadIdx.x;
  long long s1 = 0, s2 = 0;
#pragma unroll
  for (int k = 0; k < 8; ++k) {
    s1 += sum[k * COUT + co];
    s2 += (long long)sumsq[k * COUT + co];
  }
  double cnt = (double)NPIX;
  double mean = (double)s1 / cnt;
  double ex2 = (double)s2 / cnt;
  double var = ex2 - mean * mean;
  double rs = 1.0 / sqrt(var + 1e-5);
  float g = gamma[co];
  scale[co] = (float)rs * g;
  shift[co] = beta[co] - (float)(mean * rs) * g;
}

// ---------------- normalize + residual + clip (8 elems/thread) ----------------
__global__ __launch_bounds__(256) void final_kernel(const short* __restrict__ cv,
                                                    const float* __restrict__ x,
                                                    const float* __restrict__ scale,
                                                    const float* __restrict__ shift,
                                                    float* __restrict__ out) {
  size_t i = ((size_t)blockIdx.x * 256 + threadIdx.x) * 8;
  int co = (int)((i >> 10) & 255);
  size_t n = i >> 18;
  size_t hw = i & 1023;
  short4 c0 = *reinterpret_cast<const short4*>(cv + i);
  short4 c1 = *reinterpret_cast<const short4*>(cv + i + 4);
  const float* xr = x + ((n * CIN + co) << 10) + hw;
  float4 r0 = *reinterpret_cast<const float4*>(xr);
  float4 r1 = *reinterpret_cast<const float4*>(xr + 4);
  float sc = scale[co], sh = shift[co];
  float4 o0, o1;
  o0.x = fminf(1.f, fmaxf(-1.f, (float)c0.x * sc + sh + r0.x));
  o0.y = fminf(1.f, fmaxf(-1.f, (float)c0.y * sc + sh + r0.y));
  o0.z = fminf(1.f, fmaxf(-1.f, (float)c0.z * sc + sh + r0.z));
  o0.w = fminf(1.f, fmaxf(-1.f, (float)c0.w * sc + sh + r0.w));
  o1.x = fminf(1.f, fmaxf(-1.f, (float)c1.x * sc + sh + r1.x));
  o1.y = fminf(1.f, fmaxf(-1.f, (float)c1.y * sc + sh + r1.y));
  o1.z = fminf(1.f, fmaxf(-1.f, (float)c1.z * sc + sh + r1.z));
  o1.w = fminf(1.f, fmaxf(-1.f, (float)c1.w * sc + sh + r1.w));
  *reinterpret_cast<float4*>(out + i) = o0;
  *reinterpret_cast<float4*>(out + i + 4) = o1;
}

extern "C" void kernel_launch(void* const* d_in, const int* in_sizes, int n_in,
                              void* d_out, int out_size, void* d_ws, size_t ws_size,
                              hipStream_t stream) {
  const float* x     = (const float*)d_in[0];
  const float* W     = (const float*)d_in[1];
  const float* gamma = (const float*)d_in[2];
  const float* beta  = (const float*)d_in[3];
  float* out = (float*)d_out;
  char* ws = (char*)d_ws;

  signed char* xb = (signed char*)(ws + OFF_XB);
  signed char* wb = (signed char*)(ws + OFF_WB);
  short* cv = (short*)(ws + OFF_CONV);
  int* sum = (int*)(ws + OFF_STATS);
  unsigned long long* sumsq = (unsigned long long*)(ws + OFF_STATS + 8192);
  float* scale = (float*)(ws + OFF_SCALE);
  float* shift = (float*)(ws + OFF_SHIFT);
  signed char* zp = (signed char*)(ws + OFF_ZERO);

  // allow 128 KB dynamic LDS (host-side metadata; capture-safe, idempotent)
  hipFuncSetAttribute((const void*)conv_kernel,
                      hipFuncAttributeMaxDynamicSharedMemorySize, LDS_TOTAL);

  // zero shadows + scale/shift + 1 KB zero page (27,648 B)
  hipMemsetAsync(ws + OFF_STATS, 0, 27648, stream);

  pack_x_kernel<<<NBATCH * HWDIM, 256, 0, stream>>>(x, xb);
  pack_w_kernel<<<(9 * COUT * CIN) / 256, 256, 0, stream>>>(W, wb);
  conv_kernel<<<NPIX / BM, 512, LDS_TOTAL, stream>>>(xb, wb, cv, zp, sum, sumsq);
  stats_kernel<<<1, 256, 0, stream>>>(sum, sumsq, gamma, beta, scale, shift);
  final_kernel<<<(NBATCH * COUT * PIX_PER_IMG) / (256 * 8), 256, 0, stream>>>(
      cv, x, scale, shift, out);
}